// Round 18
// baseline (799.862 us; speedup 1.0000x reference)
//
#include <hip/hip_runtime.h>
#include <hip/hip_bf16.h>
#include <cstring>

// ---- problem constants ----
#define NB 8
#define NT 64
#define NNODE 24
#define ND 6
#define NH 128
#define NR 64
#define NNE 4
#define NEDGE 552                  // NNODE*(NNODE-1)
#define NSEQ (NB*NEDGE)            // 4416
#define ROWS1 (NB*NNODE*NT)        // 12288
#define ROWS2 (NB*NEDGE*NT)        // 282624
#define PRIOR_SZ (NB*NT*NEDGE*NNE) // 1130496
#define NPART 128                  // partial-reduction buffers per BN stage

typedef __hip_bfloat16 bf16;
typedef unsigned short u16;
typedef unsigned int u32;
typedef _Float16 f16;
typedef __attribute__((ext_vector_type(2))) _Float16 f16x2;
typedef __attribute__((ext_vector_type(8))) _Float16 f16x8;
typedef __attribute__((ext_vector_type(4))) float f32x4;

#if defined(__has_builtin)
#if __has_builtin(__builtin_amdgcn_fdot2)
#define HAS_DOT2 1
#endif
#if __has_builtin(__builtin_amdgcn_cvt_pkrtz)
#define HAS_PKRTZ 1
#endif
#if __has_builtin(__builtin_amdgcn_rcpf)
#define HAS_RCPF 1
#endif
#endif

#define SBAR() __builtin_amdgcn_sched_barrier(0)

__device__ __forceinline__ float rcpf(float x){
#ifdef HAS_RCPF
  return __builtin_amdgcn_rcpf(x);   // v_rcp_f32, ~1ulp
#else
  return 1.f/x;
#endif
}
// fast ELU: v_exp path instead of libm expm1 (error << f16 quantization)
__device__ __forceinline__ float eluf(float x){ return x > 0.f ? x : __expf(x) - 1.f; }
__device__ __forceinline__ float sigmf(float x){ return rcpf(1.f + __expf(-x)); }
__device__ __forceinline__ float tanhfast(float x){
  const float xc = fminf(fmaxf(x, -30.f), 30.f);   // avoid inf-inf NaN
  const float e = __expf(-2.f*xc);
  return (1.f - e)*rcpf(1.f + e);
}
__device__ __forceinline__ float b2f(bf16 v){ return __bfloat162float(v); }
__device__ __forceinline__ u16 f2h(float x){ f16 h = (f16)x; u16 v; __builtin_memcpy(&v, &h, 2); return v; }
__device__ __forceinline__ float h2f(u16 v){ f16 h; __builtin_memcpy(&h, &v, 2); return (float)h; }
__device__ __forceinline__ u32 packf2(float a, float b){ return (u32)f2h(a) | ((u32)f2h(b) << 16); }
__device__ __forceinline__ float bl2f(u16 v){ u32 b = (u32)v << 16; float f; __builtin_memcpy(&f, &b, 4); return f; }

#ifdef HAS_DOT2
__device__ __forceinline__ float dot2(u32 a, u32 b, float c){
  f16x2 av, bv;
  __builtin_memcpy(&av, &a, 4); __builtin_memcpy(&bv, &b, 4);
  return __builtin_amdgcn_fdot2(av, bv, c, false);
}
#else
__device__ __forceinline__ float dot2(u32 a, u32 b, float c){
  return c + h2f((u16)a)*h2f((u16)b) + h2f((u16)(a>>16))*h2f((u16)(b>>16));
}
#endif

// bf16 pair (packed in u32) -> f16 pair (packed in u32); bf16->f16 is exact in-range
__device__ __forceinline__ u32 bf2h2(u32 v){
  float lo, hi;
  u32 lb = v << 16, hb = v & 0xffff0000u;
  __builtin_memcpy(&lo, &lb, 4); __builtin_memcpy(&hi, &hb, 4);
#ifdef HAS_PKRTZ
  auto p = __builtin_amdgcn_cvt_pkrtz(lo, hi);
  u32 r; __builtin_memcpy(&r, &p, 4); return r;
#else
  return packf2(lo, hi);
#endif
}

// Fragment-ordered B-table index (see round 12).
__device__ __forceinline__ int fragidx(int n, int k, int NKS){
  const int nt = n >> 4, mm = n & 15;
  const int ks = k >> 5, gg = (k >> 3) & 3, jj = k & 7;
  return (((nt*NKS + ks)*64 + gg*16 + mm) << 3) | jj;
}

// ---------------- diagnostics / setup ----------------
__global__ void k_fill(float* out, int n, float pat){
  const int i = blockIdx.x*256 + threadIdx.x;
  if(i < n) out[i] = pat;
}

// transpose ALL layer-2 weights to frag-ordered f16; zero the BN partials.
__global__ void k_prep_mlp(const float* w1b, const float* w2b,
                           const float* w3b, const float* w4b,
                           u16* W2t1, u16* W2t2, u16* W2t3, u16* W2t4,
                           float* part)
{
  const int i = blockIdx.x*256 + threadIdx.x;
  for(int z = i; z < 4*NPART*256; z += 64*256) part[z] = 0.f;
  if(i < 128*128){
    const int n = i >> 7, k = i & 127;
    const int idx = fragidx(n, k, 4);
    W2t1[idx] = f2h(w1b[k*NH + n]);
    W2t2[idx] = f2h(w2b[k*NH + n]);
    W2t3[idx] = f2h(w3b[k*NH + n]);
    W2t4[idx] = f2h(w4b[k*NH + n]);
  }
}

// Fold BN into layer-1 weights, writing fragment-ordered.
__global__ __launch_bounds__(128) void k_fold(
    const float* w, int kin, float scmul,
    const float* scA, const float* shA,
    const float* scB, const float* shB,
    const float* b1, u16* Wf, float* bf)
{
  const int n = blockIdx.x, t = threadIdx.x;
  __shared__ float red[128];
  float acc = 0.f;
  const int pages = kin >> 7;
  const int NKS = kin >> 5;
  for(int p = 0; p < pages; p++){
    const int k = p*128 + t;
    const float wv = w[k*NH + n];
    const float s  = (p < 2 ? scA[t] : scB[t]);
    const float sh = (p < 2 ? shA[t] : shB[t]);
    Wf[fragidx(n, k, NKS)] = f2h(wv*s*scmul);
    acc += sh*wv;
  }
  red[t] = acc;
  __syncthreads();
  for(int o = 64; o > 0; o >>= 1){ if(t < o) red[t] += red[t+o]; __syncthreads(); }
  if(t == 0) bf[n] = b1[n] + red[0];
}

// GRU weight prep (runs after k_bn of MLP4; X region dead).
__global__ void k_prep2(const float* wihF, const float* whhF,
                        const float* wihR, const float* whhR,
                        const float* sc4, const float* sh4,
                        const float* bihF, const float* bihR,
                        u16* W2F, u16* W2R, float* b2F, float* b2R,
                        u32* whhPF, u32* whhPR)
{
  const int i = blockIdx.x*256 + threadIdx.x;
  if(i < 192*128){
    const int r = i >> 7, k = i & 127;
    const float s = sc4[k];
    const int idx = fragidx(r, k, 4);
    W2F[idx] = f2h(s*wihF[i]);
    W2R[idx] = f2h(s*wihR[i]);
  }
  if(i < 192*32){
    const int r = i >> 5, k2 = i & 31;
    whhPF[k2*192 + r] = packf2(whhF[r*NR + 2*k2], whhF[r*NR + 2*k2 + 1]);
    whhPR[k2*192 + r] = packf2(whhR[r*NR + 2*k2], whhR[r*NR + 2*k2 + 1]);
  }
  if(i < 384){
    const int d = i / 192, r = i - d*192;
    const float* wih = d ? wihR : wihF;
    const float* bih = d ? bihR : bihF;
    float s = bih[r];
    for(int k = 0; k < NH; k++) s += sh4[k]*wih[r*NH + k];
    (d ? b2R : b2F)[r] = s;
  }
}

// ---- shared layer-2: Hs(swizzled f16) @ W2t(frag-ordered) -> ELU -> out ----
template<bool F32OUT>
__device__ __forceinline__ void layer2_out(
  const u16 (*Hs)[NH], int w, int m, int g, int g0, int pbofs,
  const u16* W2t, const float* b2, void* Out, float* part)
{
  const int l = g*16 + m;
  f16x8 af2[4];
  #pragma unroll
  for(int ks = 0; ks < 4; ks++){
    const int c8 = (ks*4 + g) ^ (m & 7);
    af2[ks] = *(const f16x8*)&Hs[w*16 + m][c8*8];
  }
  f32x4 acc[8];
  #pragma unroll
  for(int nt = 0; nt < 8; nt++){
    const float bb = b2[nt*16 + m];
    acc[nt] = (f32x4){bb, bb, bb, bb};
  }
  f16x8 bf0[8], bf1[8];
  #pragma unroll
  for(int nt = 0; nt < 8; nt++)
    bf0[nt] = *(const f16x8*)&W2t[(((nt*4 + 0)*64 + l) << 3)];
  #pragma unroll
  for(int ks = 0; ks < 4; ks++){
    f16x8* cur = (ks & 1) ? bf1 : bf0;
    f16x8* nxt = (ks & 1) ? bf0 : bf1;
    if(ks + 1 < 4){
      #pragma unroll
      for(int nt = 0; nt < 8; nt++)
        nxt[nt] = *(const f16x8*)&W2t[(((nt*4 + ks + 1)*64 + l) << 3)];
    }
    SBAR();
    #pragma unroll
    for(int nt = 0; nt < 8; nt++)
      acc[nt] = __builtin_amdgcn_mfma_f32_16x16x32_f16(af2[ks], cur[nt], acc[nt], 0, 0, 0);
    SBAR();
  }
  float aS[8], aQ[8];
  #pragma unroll
  for(int nt = 0; nt < 8; nt++){
    float s = 0.f, q = 0.f;
    #pragma unroll
    for(int r = 0; r < 4; r++){
      const float h2 = eluf(acc[nt][r]);
      const size_t idx = (size_t)(g0 + w*16 + g*4 + r)*NH + nt*16 + m;
      if constexpr(F32OUT) ((float*)Out)[idx] = h2;
      else                 ((bf16*)Out)[idx] = __float2bfloat16(h2);
      s += h2; q += h2*h2;
    }
    aS[nt] = s; aQ[nt] = q;
  }
  #pragma unroll
  for(int nt = 0; nt < 8; nt++){
    float s = aS[nt], q = aQ[nt];
    s += __shfl_xor(s, 16); s += __shfl_xor(s, 32);
    q += __shfl_xor(q, 16); q += __shfl_xor(q, 32);
    if(g == 0){
      atomicAdd(&part[pbofs + nt*16 + m], s);
      atomicAdd(&part[pbofs + 128 + nt*16 + m], q);
    }
  }
}

// ---------------- MLP1 via MFMA layer-2: (B,N,T,D)->H->H ----------------------
__global__ __launch_bounds__(128) void k_mlp1(
    const float* inp, const float* w1, const float* b1,
    const u16* W2t, const float* b2,
    float* X1, float* part)
{
  __shared__ __align__(16) u16 Hs[32][NH];   // 8 KB swizzled
  __shared__ float xs[32][8];
  const int j = threadIdx.x;
  const int g0 = blockIdx.x*32;
  const int b = g0/(NNODE*NT); const int rem = g0 - b*(NNODE*NT);
  const int n = rem/NT; const int t0 = rem - n*NT;
  for(int i = j; i < 32*ND; i += 128){
    const int r = i/ND, d = i - r*ND;
    xs[r][d] = inp[((b*NT + (t0 + r))*NNODE + n)*ND + d];
  }
  __syncthreads();
  float wcol[ND];
  #pragma unroll
  for(int d = 0; d < ND; d++) wcol[d] = w1[d*NH + j];
  const float b1j = b1[j];
  for(int r = 0; r < 32; r++){
    float a = b1j;
    #pragma unroll
    for(int d = 0; d < ND; d++) a += xs[r][d]*wcol[d];
    Hs[r][((((j>>3) ^ (r&7))<<3) | (j&7))] = f2h(eluf(a));
  }
  __syncthreads();
  const int w = j >> 6, l = j & 63;
  const int m = l & 15, g = l >> 4;
  layer2_out<true>(Hs, w, m, g, g0, (blockIdx.x & (NPART-1))*256,
                   W2t, b2, X1, part);
}

// ---------------- BN params (reduce NPART partials first) ----------------
__global__ void k_bn(const float* part, const float* g, const float* be,
                     float inv_cnt, float* sc, float* sh)
{
  const int j = threadIdx.x;
  float s = 0.f, q = 0.f;
  for(int p = 0; p < NPART; p++){
    s += part[p*256 + j];
    q += part[p*256 + 128 + j];
  }
  const float m = s*inv_cnt;
  const float v = fmaxf(q*inv_cnt - m*m, 0.f);
  const float sc_ = g[j]*rsqrtf(v + 1e-5f);
  sc[j] = sc_; sh[j] = be[j] - m*sc_;
}

// ---------------- edge MLPs: no A-staging, frag weights, pipelined loads -----
template<int KIN>
__device__ __forceinline__ void edge_v2(
  const float* Xn, const bf16* Ein,
  const u16* W1f, const float* b1f, const u16* W2t, const float* b2,
  bf16* Eo, float* part)
{
  constexpr int NKS = KIN/32;
  __shared__ __align__(16) u16 Hs[64][NH];    // 16 KB, swizzled
  const int j = threadIdx.x;
  const int w = j >> 6, l = j & 63;
  const int m = l & 15, g = l >> 4;
  const int g0 = blockIdx.x*64;
  const int b = g0/(NEDGE*NT); const int rem = g0 - b*(NEDGE*NT);
  const int e = rem/NT; const int t0 = rem - e*NT;
  const int snd = e/23, r0e = e - snd*23;
  const int rcv = r0e + (r0e >= snd ? 1 : 0);
  const int tr = t0 + w*16 + m;
  const float* rowS = Xn + (size_t)((b*NNODE + snd)*NT + tr)*NH;
  const float* rowR = Xn + (size_t)((b*NNODE + rcv)*NT + tr)*NH;

  f16x8 af[NKS];
  #pragma unroll
  for(int ks = 0; ks < 4; ks++){
    const float4 a = *(const float4*)(rowS + ks*32 + g*8);
    const float4 c = *(const float4*)(rowS + ks*32 + g*8 + 4);
    u32 t4[4] = { packf2(a.x,a.y), packf2(a.z,a.w), packf2(c.x,c.y), packf2(c.z,c.w) };
    __builtin_memcpy(&af[ks], t4, 16);
  }
  #pragma unroll
  for(int ks = 4; ks < 8; ks++){
    const float4 a = *(const float4*)(rowR + (ks-4)*32 + g*8);
    const float4 c = *(const float4*)(rowR + (ks-4)*32 + g*8 + 4);
    u32 t4[4] = { packf2(a.x,a.y), packf2(a.z,a.w), packf2(c.x,c.y), packf2(c.z,c.w) };
    __builtin_memcpy(&af[ks], t4, 16);
  }
  if constexpr(KIN == 3*NH){
    const bf16* rowE = Ein + (size_t)(g0 + w*16 + m)*NH;
    #pragma unroll
    for(int ks = 8; ks < 12; ks++){
      const uint4 rv = *(const uint4*)(rowE + (ks-8)*32 + g*8);
      u32 t4[4] = { bf2h2(rv.x), bf2h2(rv.y), bf2h2(rv.z), bf2h2(rv.w) };
      __builtin_memcpy(&af[ks], t4, 16);
    }
  }

  // ---- layer 1: pipelined ks loop ----
  f32x4 acc[8];
  #pragma unroll
  for(int nt = 0; nt < 8; nt++){
    const float bb = b1f[nt*16 + m];
    acc[nt] = (f32x4){bb, bb, bb, bb};
  }
  f16x8 bf0[8], bf1[8];
  #pragma unroll
  for(int nt = 0; nt < 8; nt++)
    bf0[nt] = *(const f16x8*)&W1f[(((nt*NKS + 0)*64 + l) << 3)];
  #pragma unroll
  for(int ks = 0; ks < NKS; ks++){
    f16x8* cur = (ks & 1) ? bf1 : bf0;
    f16x8* nxt = (ks & 1) ? bf0 : bf1;
    if(ks + 1 < NKS){
      #pragma unroll
      for(int nt = 0; nt < 8; nt++)
        nxt[nt] = *(const f16x8*)&W1f[(((nt*NKS + ks + 1)*64 + l) << 3)];
    }
    SBAR();
    #pragma unroll
    for(int nt = 0; nt < 8; nt++)
      acc[nt] = __builtin_amdgcn_mfma_f32_16x16x32_f16(af[ks], cur[nt], acc[nt], 0, 0, 0);
    SBAR();
  }
  #pragma unroll
  for(int nt = 0; nt < 8; nt++){
    #pragma unroll
    for(int r = 0; r < 4; r++){
      const int row = g*4 + r;
      const int c8 = (nt*2 + (m >> 3)) ^ (row & 7);
      Hs[w*16 + row][c8*8 + (m & 7)] = f2h(eluf(acc[nt][r]));
    }
  }
  __syncthreads();
  layer2_out<false>(Hs, w, m, g, g0, (blockIdx.x & (NPART-1))*256,
                    W2t, b2, Eo, part);
}

__global__ __launch_bounds__(256, 2) void k_edge2(
  const float* Xn, const u16* W1f, const float* b1f,
  const u16* W2t, const float* b2,
  bf16* Eo, float* part)
{
  edge_v2<2*NH>(Xn, nullptr, W1f, b1f, W2t, b2, Eo, part);
}
__global__ __launch_bounds__(256, 2) void k_edge4(
  const float* Xn, const bf16* Ein, const u16* W1f, const float* b1f,
  const u16* W2t, const float* b2,
  bf16* Eo, float* part)
{
  edge_v2<3*NH>(Xn, Ein, W1f, b1f, W2t, b2, Eo, part);
}

// ---------------- MLP3 via MFMA: agg(mean of 23 edges) -> H -> H --------------
__global__ __launch_bounds__(128) void k_mlp3(
    const bf16* Ein, const u16* W1f, const float* b1f,
    const u16* W2t, const float* b2,
    float* X3, float* part)
{
  __shared__ __align__(16) u16 Hs[32][NH];   // 8 KB swizzled
  const int j = threadIdx.x;
  const int w = j >> 6, l = j & 63;
  const int m = l & 15, g = l >> 4;
  const int g0 = blockIdx.x*32;
  const int b = g0/(NNODE*NT); const int rem = g0 - b*(NNODE*NT);
  const int n = rem/NT; const int t0 = rem - n*NT;
  const int tr = t0 + w*16 + m;

  float acc32[4][8];
  #pragma unroll
  for(int ks = 0; ks < 4; ks++)
    #pragma unroll
    for(int q = 0; q < 8; q++) acc32[ks][q] = 0.f;
  for(int i = 0; i < NNODE; i++){
    if(i == n) continue;
    const int e = i*23 + (n < i ? n : n - 1);
    const bf16* rowE = Ein + ((size_t)(b*NEDGE + e)*NT + tr)*NH;
    #pragma unroll
    for(int ks = 0; ks < 4; ks++){
      const uint4 rv = *(const uint4*)(rowE + ks*32 + g*8);
      const u32 vv[4] = {rv.x, rv.y, rv.z, rv.w};
      #pragma unroll
      for(int h = 0; h < 4; h++){
        acc32[ks][2*h]   += bl2f((u16)vv[h]);
        acc32[ks][2*h+1] += bl2f((u16)(vv[h] >> 16));
      }
    }
  }
  f16x8 af[4];
  #pragma unroll
  for(int ks = 0; ks < 4; ks++){
    u32 t4[4] = { packf2(acc32[ks][0], acc32[ks][1]), packf2(acc32[ks][2], acc32[ks][3]),
                  packf2(acc32[ks][4], acc32[ks][5]), packf2(acc32[ks][6], acc32[ks][7]) };
    __builtin_memcpy(&af[ks], t4, 16);
  }

  f32x4 acc[8];
  #pragma unroll
  for(int nt = 0; nt < 8; nt++){
    const float bb = b1f[nt*16 + m];
    acc[nt] = (f32x4){bb, bb, bb, bb};
  }
  f16x8 bf0[8], bf1[8];
  #pragma unroll
  for(int nt = 0; nt < 8; nt++)
    bf0[nt] = *(const f16x8*)&W1f[(((nt*4 + 0)*64 + l) << 3)];
  #pragma unroll
  for(int ks = 0; ks < 4; ks++){
    f16x8* cur = (ks & 1) ? bf1 : bf0;
    f16x8* nxt = (ks & 1) ? bf0 : bf1;
    if(ks + 1 < 4){
      #pragma unroll
      for(int nt = 0; nt < 8; nt++)
        nxt[nt] = *(const f16x8*)&W1f[(((nt*4 + ks + 1)*64 + l) << 3)];
    }
    SBAR();
    #pragma unroll
    for(int nt = 0; nt < 8; nt++)
      acc[nt] = __builtin_amdgcn_mfma_f32_16x16x32_f16(af[ks], cur[nt], acc[nt], 0, 0, 0);
    SBAR();
  }
  #pragma unroll
  for(int nt = 0; nt < 8; nt++){
    #pragma unroll
    for(int r = 0; r < 4; r++){
      const int row = g*4 + r;
      const int c8 = (nt*2 + (m >> 3)) ^ (row & 7);
      Hs[w*16 + row][c8*8 + (m & 7)] = f2h(eluf(acc[nt][r]));
    }
  }
  __syncthreads();
  layer2_out<true>(Hs, w, m, g, g0, (blockIdx.x & (NPART-1))*256,
                   W2t, b2, X3, part);
}

// ---------------- GRU: 4 independent (seq,dir) units per 256-thread block -----
// Round 18: (256,1) -> VGPR budget 512; round 17's (256,2) capped at 128 and
// spilled part of the whh arrays (WRITE_SIZE +7.9MB). ~150-170 live regs fit
// without spill; LDS still allows 4 blocks/CU.
__global__ __launch_bounds__(256, 1) void k_gru(
  const bf16* E4,
  const u16* W2F, const float* b2F, const u32* whhPF, const float* bhhF,
  const u16* W2R, const float* b2R, const u32* whhPR, const float* bhhR,
  const float* pw, const float* pb, const float* ew,
  bf16* encpF, bf16* encpR, float* outP, float* hT)
{
  __shared__ __align__(16) u16 xwb16[4][16][196];  // 25088 B (padded rows)
  __shared__ __align__(16) u16 histc[4][16][66];   // 8448 B (chunk-local history)
  __shared__ __align__(16) u16 hs16[4][NR];        // 512 B
  const int tid = threadIdx.x;
  const int u = tid >> 6, c = tid & 63;
  const int gid = blockIdx.x*4 + u;
  const int dir = (gid >= NSEQ) ? 1 : 0;
  const int s = dir ? (gid - NSEQ) : gid;
  const int sb = s / NEDGE, se = s - sb*NEDGE;
  const u16* W2    = dir ? W2R : W2F;
  const float* b2  = dir ? b2R : b2F;
  const u32* whhP  = dir ? whhPR : whhPF;
  const float* bhh = dir ? bhhR : bhhF;
  const float bhr = bhh[c], bhz = bhh[64+c], bhn = bhh[128+c];
  const int m = c & 15, g = c >> 4;   // MFMA lane decomposition

  hs16[u][c] = 0;
  float hprev = 0.f;

  for(int T = 0; T < 4; T++){
    const int t_m = dir ? (NT - 1 - (T*16 + m)) : (T*16 + m);
    const bf16* arow = E4 + ((size_t)s*NT + t_m)*NH;
    f16x8 afr[4];
    #pragma unroll
    for(int ks = 0; ks < 4; ks++){
      const uint4 rv = *(const uint4*)(arow + ks*32 + g*8);
      u32 tmp[4] = { bf2h2(rv.x), bf2h2(rv.y), bf2h2(rv.z), bf2h2(rv.w) };
      f16x8 a; __builtin_memcpy(&a, tmp, 16);
      afr[ks] = a;
    }
    for(int nt = 0; nt < 12; nt++){
      f32x4 acc = {0.f, 0.f, 0.f, 0.f};
      #pragma unroll
      for(int ks = 0; ks < 4; ks++){
        const f16x8 bfr = *(const f16x8*)&W2[(((nt*4 + ks)*64 + c) << 3)];
        acc = __builtin_amdgcn_mfma_f32_16x16x32_f16(afr[ks], bfr, acc, 0, 0, 0);
      }
      const float bb = b2[nt*16 + m];
      #pragma unroll
      for(int r = 0; r < 4; r++)
        xwb16[u][g*4 + r][nt*16 + m] = f2h(acc[r] + bb);
    }
    u32 zofs = 0;
    asm volatile("" : "+v"(zofs));       // opaque VGPR zero: prevent hoist/CSE
    const u32* wPt = whhP + zofs;
    u32 wr2[32], wz2[32], wn2[32];
    #pragma unroll
    for(int kk = 0; kk < 32; kk++){
      wr2[kk] = wPt[kk*192 + c];
      wz2[kk] = wPt[kk*192 + 64 + c];
      wn2[kk] = wPt[kk*192 + 128 + c];
    }
    for(int pp = 0; pp < 16; pp++){
      const float xr = h2f(xwb16[u][pp][c]);
      const float xz = h2f(xwb16[u][pp][64 + c]);
      const float xn = h2f(xwb16[u][pp][128 + c]);
      float hr = bhr, hz = bhz, hn = bhn;
      #pragma unroll
      for(int q = 0; q < 8; q++){
        const uint4 hq = *(const uint4*)&hs16[u][8*q];
        hr = dot2(hq.x, wr2[4*q], hr);   hr = dot2(hq.y, wr2[4*q+1], hr);
        hr = dot2(hq.z, wr2[4*q+2], hr); hr = dot2(hq.w, wr2[4*q+3], hr);
        hz = dot2(hq.x, wz2[4*q], hz);   hz = dot2(hq.y, wz2[4*q+1], hz);
        hz = dot2(hq.z, wz2[4*q+2], hz); hz = dot2(hq.w, wz2[4*q+3], hz);
        hn = dot2(hq.x, wn2[4*q], hn);   hn = dot2(hq.y, wn2[4*q+1], hn);
        hn = dot2(hq.z, wn2[4*q+2], hn); hn = dot2(hq.w, wn2[4*q+3], hn);
      }
      const float rg = sigmf(xr + hr);
      const float zg = sigmf(xz + hz);
      const float ng = tanhfast(xn + rg*hn);
      const float hnew = (1.f - zg)*ng + zg*hprev;
      const u16 hbits = f2h(hnew);
      hs16[u][c] = hbits; hprev = hnew;
      histc[u][pp][c] = hbits;
    }
    {
      const int tt = c & 15, grp = c >> 4;
      const int p0 = T*16 + tt;
      const int tg = dir ? (NT - 1 - p0) : p0;
      if(!dir){
        float ap = pb[grp], ae = 0.f;
        for(int kk = 0; kk < 32; kk++){
          u32 hp; __builtin_memcpy(&hp, &histc[u][tt][2*kk], 4);
          const float h0 = h2f((u16)hp), h1 = h2f((u16)(hp >> 16));
          ap += h0*pw[(2*kk)*NNE + grp] + h1*pw[(2*kk+1)*NNE + grp];
          ae += h0*ew[(2*kk)*NNE + grp] + h1*ew[(2*kk+1)*NNE + grp];
        }
        outP[(((size_t)(sb*NT + tg))*NEDGE + se)*NNE + grp] = ap;
        encpF[((size_t)s*NT + tg)*NNE + grp] = __float2bfloat16(ae);
      } else {
        float ae = 0.f;
        for(int kk = 0; kk < 32; kk++){
          u32 hp; __builtin_memcpy(&hp, &histc[u][tt][2*kk], 4);
          const float h0 = h2f((u16)hp), h1 = h2f((u16)(hp >> 16));
          ae += h0*ew[(NR + 2*kk)*NNE + grp] + h1*ew[(NR + 2*kk+1)*NNE + grp];
        }
        encpR[((size_t)s*NT + tg)*NNE + grp] = __float2bfloat16(ae);
      }
    }
  }
  if(!dir) hT[(size_t)s*NR + c] = hprev;
}

// ---------------- merge enc halves + bias ----------------
__global__ void k_add(const bf16* eF, const bf16* eR, const float* eb, float* outE){
  const int i = blockIdx.x*256 + threadIdx.x;
  if(i >= PRIOR_SZ) return;
  const int l = i & 3; const int r2 = i >> 2;
  const int e = r2 % NEDGE; const int r3 = r2 / NEDGE;
  const int t = r3 % NT; const int b = r3 / NT;
  const int s = b*NEDGE + e;
  const size_t src = ((size_t)s*NT + t)*NNE + l;
  outE[i] = b2f(eF[src]) + b2f(eR[src]) + eb[l];
}

extern "C" void kernel_launch(void* const* d_in, const int* in_sizes, int n_in,
                              void* d_out, int out_size, void* d_ws, size_t ws_size,
                              hipStream_t stream)
{
  const size_t NEED = 79511552ull;   // unchanged; known ws >= 83,181,568
  if(ws_size < NEED){
    k_fill<<<(out_size + 255)/256, 256, 0, stream>>>((float*)d_out, out_size, 3584.0f);
    return;
  }
  const float* inp  = (const float*)d_in[0];
  const float* m1w1 = (const float*)d_in[1];  const float* m1b1 = (const float*)d_in[2];
  const float* m1w2 = (const float*)d_in[3];  const float* m1b2 = (const float*)d_in[4];
  const float* m1g  = (const float*)d_in[5];  const float* m1be = (const float*)d_in[6];
  const float* m2w1 = (const float*)d_in[7];  const float* m2b1 = (const float*)d_in[8];
  const float* m2w2 = (const float*)d_in[9];  const float* m2b2 = (const float*)d_in[10];
  const float* m2g  = (const float*)d_in[11]; const float* m2be = (const float*)d_in[12];
  const float* m3w1 = (const float*)d_in[13]; const float* m3b1 = (const float*)d_in[14];
  const float* m3w2 = (const float*)d_in[15]; const float* m3b2 = (const float*)d_in[16];
  const float* m3g  = (const float*)d_in[17]; const float* m3be = (const float*)d_in[18];
  const float* m4w1 = (const float*)d_in[19]; const float* m4b1 = (const float*)d_in[20];
  const float* m4w2 = (const float*)d_in[21]; const float* m4b2 = (const float*)d_in[22];
  const float* m4g  = (const float*)d_in[23]; const float* m4be = (const float*)d_in[24];
  const float* wihF = (const float*)d_in[25]; const float* whhF = (const float*)d_in[26];
  const float* bihF = (const float*)d_in[27]; const float* bhhF = (const float*)d_in[28];
  const float* wihR = (const float*)d_in[29]; const float* whhR = (const float*)d_in[30];
  const float* bihR = (const float*)d_in[31]; const float* bhhR = (const float*)d_in[32];
  const float* pw   = (const float*)d_in[33]; const float* pb   = (const float*)d_in[34];
  const float* ew   = (const float*)d_in[35]; const float* eb   = (const float*)d_in[36];

  char* ws = (char*)d_ws;
  float* AUX = (float*)(ws + 0);             // 16 KB reserved (SC/SH/B1F)
  char*  Xr  = ws + 16384;                   // 6,291,456 B (X1 then X3)
  float* X   = (float*)Xr;
  bf16*  E   = (bf16*)(ws + 16384 + 6291456); // 72,351,744 B (E2 then in-place E4)
  char*  WP  = ws + 78659584;                // 327,680 B MLP weight tables (frag-ordered)
  u16* W1f2 = (u16*)(WP + 0);                // 65,536 B (128 x 256, BN-folded)
  u16* W2t2 = (u16*)(WP + 65536);            // 32,768 B
  u16* W1f4 = (u16*)(WP + 98304);            // 98,304 B (128 x 384, BN-folded)
  u16* W2t4 = (u16*)(WP + 196608);           // 32,768 B
  u16* W2t1 = (u16*)(WP + 229376);           // 32,768 B
  u16* W2t3 = (u16*)(WP + 262144);           // 32,768 B
  u16* W1f3 = (u16*)(WP + 294912);           // 32,768 B (128 x 128, BN/23-folded)
  float* PART = (float*)(ws + 78987264);     // 524,288 B: 4 stages x NPART x 256 f32
  float* P0 = PART + 0*NPART*256;
  float* P1 = PART + 1*NPART*256;
  float* P2 = PART + 2*NPART*256;
  float* P3 = PART + 3*NPART*256;
  // aliases inside X region, valid AFTER mlp4 has consumed X3:
  u16*  W2F   = (u16*)(Xr + 0);              // 49,152 B (BN-folded wih fwd, frag-ordered)
  u16*  W2R   = (u16*)(Xr + 49152);          // 49,152 B -> 98,304
  u32*  whhPF = (u32*)(Xr + 98304);          // 24,576 B -> 122,880
  u32*  whhPR = (u32*)(Xr + 122880);         // 24,576 B -> 147,456
  float* b2F  = (float*)(Xr + 147456);       // 768 B -> 148,224
  float* b2R  = (float*)(Xr + 148224);       // 768 B -> 148,992
  bf16* encpF = (bf16*)(Xr + 148992);        // 2,260,992 B -> 2,409,984
  bf16* encpR = (bf16*)(Xr + 2409984);       // 2,260,992 B -> 4,670,976 <= 6,291,456

  float* SC0  = AUX + 1024 + 0*128; float* SC1  = AUX + 1024 + 1*128;
  float* SC2  = AUX + 1024 + 2*128; float* SC3  = AUX + 1024 + 3*128;
  float* SH0  = AUX + 1536 + 0*128; float* SH1  = AUX + 1536 + 1*128;
  float* SH2  = AUX + 1536 + 2*128; float* SH3  = AUX + 1536 + 3*128;
  float* B1F2 = AUX + 2048;                  // 128 f32 folded biases
  float* B1F4 = AUX + 2176;
  float* B1F3 = AUX + 2304;                  // -> word 2432 < 4096

  float* outP = (float*)d_out;
  float* outE = outP + PRIOR_SZ;
  float* hT   = outP + 2*PRIOR_SZ;

  k_prep_mlp<<<64, 256, 0, stream>>>(m1w2, m2w2, m3w2, m4w2,
                                     W2t1, W2t2, W2t3, W2t4, PART);
  k_mlp1<<<ROWS1/32, 128, 0, stream>>>(inp, m1w1, m1b1, W2t1, m1b2, X, P0);
  k_bn<<<1, 128, 0, stream>>>(P0, m1g, m1be, 1.f/ROWS1, SC0, SH0);
  k_fold<<<128, 128, 0, stream>>>(m2w1, 2*NH, 1.f, SC0, SH0, SC0, SH0, m2b1, W1f2, B1F2);
  k_edge2<<<ROWS2/64, 256, 0, stream>>>(X, W1f2, B1F2, W2t2, m2b2, E, P1);
  k_bn<<<1, 128, 0, stream>>>(P1, m2g, m2be, 1.f/ROWS2, SC1, SH1);
  k_fold<<<128, 128, 0, stream>>>(m3w1, NH, 1.f/23.f, SC1, SH1, SC1, SH1, m3b1, W1f3, B1F3);
  k_mlp3<<<ROWS1/32, 128, 0, stream>>>(E, W1f3, B1F3, W2t3, m3b2, X, P2);
  k_bn<<<1, 128, 0, stream>>>(P2, m3g, m3be, 1.f/ROWS1, SC2, SH2);
  k_fold<<<128, 128, 0, stream>>>(m4w1, 3*NH, 1.f, SC2, SH2, SC1, SH1, m4b1, W1f4, B1F4);
  k_edge4<<<ROWS2/64, 256, 0, stream>>>(X, E, W1f4, B1F4, W2t4, m4b2, E, P3);
  k_bn<<<1, 128, 0, stream>>>(P3, m4g, m4be, 1.f/ROWS2, SC3, SH3);
  // X region is now dead -> pack GRU weights (BN folded, frag-ordered) into it
  k_prep2<<<96, 256, 0, stream>>>(wihF, whhF, wihR, whhR, SC3, SH3, bihF, bihR,
                                  W2F, W2R, b2F, b2R, whhPF, whhPR);
  k_gru<<<(2*NSEQ)/4, 256, 0, stream>>>(E,
                                  W2F, b2F, whhPF, bhhF,
                                  W2R, b2R, whhPR, bhhR,
                                  pw, pb, ew, encpF, encpR, outP, hT);
  k_add<<<(PRIOR_SZ + 255)/256, 256, 0, stream>>>(encpF, encpR, eb, outE);
}

// Round 19
// 672.307 us; speedup vs baseline: 1.1897x; 1.1897x over previous
//
#include <hip/hip_runtime.h>
#include <hip/hip_bf16.h>
#include <cstring>

// ---- problem constants ----
#define NB 8
#define NT 64
#define NNODE 24
#define ND 6
#define NH 128
#define NR 64
#define NNE 4
#define NEDGE 552                  // NNODE*(NNODE-1)
#define NSEQ (NB*NEDGE)            // 4416
#define ROWS1 (NB*NNODE*NT)        // 12288
#define ROWS2 (NB*NEDGE*NT)        // 282624
#define PRIOR_SZ (NB*NT*NEDGE*NNE) // 1130496
#define NPART 128                  // partial-reduction buffers per BN stage

typedef __hip_bfloat16 bf16;
typedef unsigned short u16;
typedef unsigned int u32;
typedef _Float16 f16;
typedef __attribute__((ext_vector_type(2))) _Float16 f16x2;
typedef __attribute__((ext_vector_type(8))) _Float16 f16x8;
typedef __attribute__((ext_vector_type(4))) float f32x4;

#if defined(__has_builtin)
#if __has_builtin(__builtin_amdgcn_fdot2)
#define HAS_DOT2 1
#endif
#if __has_builtin(__builtin_amdgcn_cvt_pkrtz)
#define HAS_PKRTZ 1
#endif
#if __has_builtin(__builtin_amdgcn_rcpf)
#define HAS_RCPF 1
#endif
#endif

#define SBAR() __builtin_amdgcn_sched_barrier(0)

__device__ __forceinline__ float rcpf(float x){
#ifdef HAS_RCPF
  return __builtin_amdgcn_rcpf(x);   // v_rcp_f32, ~1ulp
#else
  return 1.f/x;
#endif
}
// fast ELU: v_exp path instead of libm expm1 (error << f16 quantization)
__device__ __forceinline__ float eluf(float x){ return x > 0.f ? x : __expf(x) - 1.f; }
__device__ __forceinline__ float sigmf(float x){ return rcpf(1.f + __expf(-x)); }
__device__ __forceinline__ float tanhfast(float x){
  const float xc = fminf(fmaxf(x, -30.f), 30.f);   // avoid inf-inf NaN
  const float e = __expf(-2.f*xc);
  return (1.f - e)*rcpf(1.f + e);
}
__device__ __forceinline__ float b2f(bf16 v){ return __bfloat162float(v); }
__device__ __forceinline__ u16 f2h(float x){ f16 h = (f16)x; u16 v; __builtin_memcpy(&v, &h, 2); return v; }
__device__ __forceinline__ float h2f(u16 v){ f16 h; __builtin_memcpy(&h, &v, 2); return (float)h; }
__device__ __forceinline__ u32 packf2(float a, float b){ return (u32)f2h(a) | ((u32)f2h(b) << 16); }
__device__ __forceinline__ float bl2f(u16 v){ u32 b = (u32)v << 16; float f; __builtin_memcpy(&f, &b, 4); return f; }

#ifdef HAS_DOT2
__device__ __forceinline__ float dot2(u32 a, u32 b, float c){
  f16x2 av, bv;
  __builtin_memcpy(&av, &a, 4); __builtin_memcpy(&bv, &b, 4);
  return __builtin_amdgcn_fdot2(av, bv, c, false);
}
#else
__device__ __forceinline__ float dot2(u32 a, u32 b, float c){
  return c + h2f((u16)a)*h2f((u16)b) + h2f((u16)(a>>16))*h2f((u16)(b>>16));
}
#endif

// bf16 pair (packed in u32) -> f16 pair (packed in u32); bf16->f16 is exact in-range
__device__ __forceinline__ u32 bf2h2(u32 v){
  float lo, hi;
  u32 lb = v << 16, hb = v & 0xffff0000u;
  __builtin_memcpy(&lo, &lb, 4); __builtin_memcpy(&hi, &hb, 4);
#ifdef HAS_PKRTZ
  auto p = __builtin_amdgcn_cvt_pkrtz(lo, hi);
  u32 r; __builtin_memcpy(&r, &p, 4); return r;
#else
  return packf2(lo, hi);
#endif
}

// Fragment-ordered B-table index (see round 12).
__device__ __forceinline__ int fragidx(int n, int k, int NKS){
  const int nt = n >> 4, mm = n & 15;
  const int ks = k >> 5, gg = (k >> 3) & 3, jj = k & 7;
  return (((nt*NKS + ks)*64 + gg*16 + mm) << 3) | jj;
}

// ---------------- diagnostics / setup ----------------
__global__ void k_fill(float* out, int n, float pat){
  const int i = blockIdx.x*256 + threadIdx.x;
  if(i < n) out[i] = pat;
}

// transpose ALL layer-2 weights to frag-ordered f16; zero the BN partials.
__global__ void k_prep_mlp(const float* w1b, const float* w2b,
                           const float* w3b, const float* w4b,
                           u16* W2t1, u16* W2t2, u16* W2t3, u16* W2t4,
                           float* part)
{
  const int i = blockIdx.x*256 + threadIdx.x;
  for(int z = i; z < 4*NPART*256; z += 64*256) part[z] = 0.f;
  if(i < 128*128){
    const int n = i >> 7, k = i & 127;
    const int idx = fragidx(n, k, 4);
    W2t1[idx] = f2h(w1b[k*NH + n]);
    W2t2[idx] = f2h(w2b[k*NH + n]);
    W2t3[idx] = f2h(w3b[k*NH + n]);
    W2t4[idx] = f2h(w4b[k*NH + n]);
  }
}

// Fold BN into layer-1 weights, writing fragment-ordered.
__global__ __launch_bounds__(128) void k_fold(
    const float* w, int kin, float scmul,
    const float* scA, const float* shA,
    const float* scB, const float* shB,
    const float* b1, u16* Wf, float* bf)
{
  const int n = blockIdx.x, t = threadIdx.x;
  __shared__ float red[128];
  float acc = 0.f;
  const int pages = kin >> 7;
  const int NKS = kin >> 5;
  for(int p = 0; p < pages; p++){
    const int k = p*128 + t;
    const float wv = w[k*NH + n];
    const float s  = (p < 2 ? scA[t] : scB[t]);
    const float sh = (p < 2 ? shA[t] : shB[t]);
    Wf[fragidx(n, k, NKS)] = f2h(wv*s*scmul);
    acc += sh*wv;
  }
  red[t] = acc;
  __syncthreads();
  for(int o = 64; o > 0; o >>= 1){ if(t < o) red[t] += red[t+o]; __syncthreads(); }
  if(t == 0) bf[n] = b1[n] + red[0];
}

// GRU weight prep (runs after k_bn of MLP4; X region dead).
__global__ void k_prep2(const float* wihF, const float* whhF,
                        const float* wihR, const float* whhR,
                        const float* sc4, const float* sh4,
                        const float* bihF, const float* bihR,
                        u16* W2F, u16* W2R, float* b2F, float* b2R,
                        u32* whhPF, u32* whhPR)
{
  const int i = blockIdx.x*256 + threadIdx.x;
  if(i < 192*128){
    const int r = i >> 7, k = i & 127;
    const float s = sc4[k];
    const int idx = fragidx(r, k, 4);
    W2F[idx] = f2h(s*wihF[i]);
    W2R[idx] = f2h(s*wihR[i]);
  }
  if(i < 192*32){
    const int r = i >> 5, k2 = i & 31;
    whhPF[k2*192 + r] = packf2(whhF[r*NR + 2*k2], whhF[r*NR + 2*k2 + 1]);
    whhPR[k2*192 + r] = packf2(whhR[r*NR + 2*k2], whhR[r*NR + 2*k2 + 1]);
  }
  if(i < 384){
    const int d = i / 192, r = i - d*192;
    const float* wih = d ? wihR : wihF;
    const float* bih = d ? bihR : bihF;
    float s = bih[r];
    for(int k = 0; k < NH; k++) s += sh4[k]*wih[r*NH + k];
    (d ? b2R : b2F)[r] = s;
  }
}

// ---- shared layer-2: Hs(swizzled f16) @ W2t(frag-ordered) -> ELU -> out ----
template<bool F32OUT>
__device__ __forceinline__ void layer2_out(
  const u16 (*Hs)[NH], int w, int m, int g, int g0, int pbofs,
  const u16* W2t, const float* b2, void* Out, float* part)
{
  const int l = g*16 + m;
  f16x8 af2[4];
  #pragma unroll
  for(int ks = 0; ks < 4; ks++){
    const int c8 = (ks*4 + g) ^ (m & 7);
    af2[ks] = *(const f16x8*)&Hs[w*16 + m][c8*8];
  }
  f32x4 acc[8];
  #pragma unroll
  for(int nt = 0; nt < 8; nt++){
    const float bb = b2[nt*16 + m];
    acc[nt] = (f32x4){bb, bb, bb, bb};
  }
  f16x8 bf0[8], bf1[8];
  #pragma unroll
  for(int nt = 0; nt < 8; nt++)
    bf0[nt] = *(const f16x8*)&W2t[(((nt*4 + 0)*64 + l) << 3)];
  #pragma unroll
  for(int ks = 0; ks < 4; ks++){
    f16x8* cur = (ks & 1) ? bf1 : bf0;
    f16x8* nxt = (ks & 1) ? bf0 : bf1;
    if(ks + 1 < 4){
      #pragma unroll
      for(int nt = 0; nt < 8; nt++)
        nxt[nt] = *(const f16x8*)&W2t[(((nt*4 + ks + 1)*64 + l) << 3)];
    }
    SBAR();
    #pragma unroll
    for(int nt = 0; nt < 8; nt++)
      acc[nt] = __builtin_amdgcn_mfma_f32_16x16x32_f16(af2[ks], cur[nt], acc[nt], 0, 0, 0);
    SBAR();
  }
  float aS[8], aQ[8];
  #pragma unroll
  for(int nt = 0; nt < 8; nt++){
    float s = 0.f, q = 0.f;
    #pragma unroll
    for(int r = 0; r < 4; r++){
      const float h2 = eluf(acc[nt][r]);
      const size_t idx = (size_t)(g0 + w*16 + g*4 + r)*NH + nt*16 + m;
      if constexpr(F32OUT) ((float*)Out)[idx] = h2;
      else                 ((bf16*)Out)[idx] = __float2bfloat16(h2);
      s += h2; q += h2*h2;
    }
    aS[nt] = s; aQ[nt] = q;
  }
  #pragma unroll
  for(int nt = 0; nt < 8; nt++){
    float s = aS[nt], q = aQ[nt];
    s += __shfl_xor(s, 16); s += __shfl_xor(s, 32);
    q += __shfl_xor(q, 16); q += __shfl_xor(q, 32);
    if(g == 0){
      atomicAdd(&part[pbofs + nt*16 + m], s);
      atomicAdd(&part[pbofs + 128 + nt*16 + m], q);
    }
  }
}

// ---------------- MLP1 via MFMA layer-2: (B,N,T,D)->H->H ----------------------
__global__ __launch_bounds__(128) void k_mlp1(
    const float* inp, const float* w1, const float* b1,
    const u16* W2t, const float* b2,
    float* X1, float* part)
{
  __shared__ __align__(16) u16 Hs[32][NH];   // 8 KB swizzled
  __shared__ float xs[32][8];
  const int j = threadIdx.x;
  const int g0 = blockIdx.x*32;
  const int b = g0/(NNODE*NT); const int rem = g0 - b*(NNODE*NT);
  const int n = rem/NT; const int t0 = rem - n*NT;
  for(int i = j; i < 32*ND; i += 128){
    const int r = i/ND, d = i - r*ND;
    xs[r][d] = inp[((b*NT + (t0 + r))*NNODE + n)*ND + d];
  }
  __syncthreads();
  float wcol[ND];
  #pragma unroll
  for(int d = 0; d < ND; d++) wcol[d] = w1[d*NH + j];
  const float b1j = b1[j];
  for(int r = 0; r < 32; r++){
    float a = b1j;
    #pragma unroll
    for(int d = 0; d < ND; d++) a += xs[r][d]*wcol[d];
    Hs[r][((((j>>3) ^ (r&7))<<3) | (j&7))] = f2h(eluf(a));
  }
  __syncthreads();
  const int w = j >> 6, l = j & 63;
  const int m = l & 15, g = l >> 4;
  layer2_out<true>(Hs, w, m, g, g0, (blockIdx.x & (NPART-1))*256,
                   W2t, b2, X1, part);
}

// ---------------- BN params (reduce NPART partials first) ----------------
__global__ void k_bn(const float* part, const float* g, const float* be,
                     float inv_cnt, float* sc, float* sh)
{
  const int j = threadIdx.x;
  float s = 0.f, q = 0.f;
  for(int p = 0; p < NPART; p++){
    s += part[p*256 + j];
    q += part[p*256 + 128 + j];
  }
  const float m = s*inv_cnt;
  const float v = fmaxf(q*inv_cnt - m*m, 0.f);
  const float sc_ = g[j]*rsqrtf(v + 1e-5f);
  sc[j] = sc_; sh[j] = be[j] - m*sc_;
}

// ---------------- edge MLPs: no A-staging, frag weights, pipelined loads -----
template<int KIN>
__device__ __forceinline__ void edge_v2(
  const float* Xn, const bf16* Ein,
  const u16* W1f, const float* b1f, const u16* W2t, const float* b2,
  bf16* Eo, float* part)
{
  constexpr int NKS = KIN/32;
  __shared__ __align__(16) u16 Hs[64][NH];    // 16 KB, swizzled
  const int j = threadIdx.x;
  const int w = j >> 6, l = j & 63;
  const int m = l & 15, g = l >> 4;
  const int g0 = blockIdx.x*64;
  const int b = g0/(NEDGE*NT); const int rem = g0 - b*(NEDGE*NT);
  const int e = rem/NT; const int t0 = rem - e*NT;
  const int snd = e/23, r0e = e - snd*23;
  const int rcv = r0e + (r0e >= snd ? 1 : 0);
  const int tr = t0 + w*16 + m;
  const float* rowS = Xn + (size_t)((b*NNODE + snd)*NT + tr)*NH;
  const float* rowR = Xn + (size_t)((b*NNODE + rcv)*NT + tr)*NH;

  f16x8 af[NKS];
  #pragma unroll
  for(int ks = 0; ks < 4; ks++){
    const float4 a = *(const float4*)(rowS + ks*32 + g*8);
    const float4 c = *(const float4*)(rowS + ks*32 + g*8 + 4);
    u32 t4[4] = { packf2(a.x,a.y), packf2(a.z,a.w), packf2(c.x,c.y), packf2(c.z,c.w) };
    __builtin_memcpy(&af[ks], t4, 16);
  }
  #pragma unroll
  for(int ks = 4; ks < 8; ks++){
    const float4 a = *(const float4*)(rowR + (ks-4)*32 + g*8);
    const float4 c = *(const float4*)(rowR + (ks-4)*32 + g*8 + 4);
    u32 t4[4] = { packf2(a.x,a.y), packf2(a.z,a.w), packf2(c.x,c.y), packf2(c.z,c.w) };
    __builtin_memcpy(&af[ks], t4, 16);
  }
  if constexpr(KIN == 3*NH){
    const bf16* rowE = Ein + (size_t)(g0 + w*16 + m)*NH;
    #pragma unroll
    for(int ks = 8; ks < 12; ks++){
      const uint4 rv = *(const uint4*)(rowE + (ks-8)*32 + g*8);
      u32 t4[4] = { bf2h2(rv.x), bf2h2(rv.y), bf2h2(rv.z), bf2h2(rv.w) };
      __builtin_memcpy(&af[ks], t4, 16);
    }
  }

  // ---- layer 1: pipelined ks loop ----
  f32x4 acc[8];
  #pragma unroll
  for(int nt = 0; nt < 8; nt++){
    const float bb = b1f[nt*16 + m];
    acc[nt] = (f32x4){bb, bb, bb, bb};
  }
  f16x8 bf0[8], bf1[8];
  #pragma unroll
  for(int nt = 0; nt < 8; nt++)
    bf0[nt] = *(const f16x8*)&W1f[(((nt*NKS + 0)*64 + l) << 3)];
  #pragma unroll
  for(int ks = 0; ks < NKS; ks++){
    f16x8* cur = (ks & 1) ? bf1 : bf0;
    f16x8* nxt = (ks & 1) ? bf0 : bf1;
    if(ks + 1 < NKS){
      #pragma unroll
      for(int nt = 0; nt < 8; nt++)
        nxt[nt] = *(const f16x8*)&W1f[(((nt*NKS + ks + 1)*64 + l) << 3)];
    }
    SBAR();
    #pragma unroll
    for(int nt = 0; nt < 8; nt++)
      acc[nt] = __builtin_amdgcn_mfma_f32_16x16x32_f16(af[ks], cur[nt], acc[nt], 0, 0, 0);
    SBAR();
  }
  #pragma unroll
  for(int nt = 0; nt < 8; nt++){
    #pragma unroll
    for(int r = 0; r < 4; r++){
      const int row = g*4 + r;
      const int c8 = (nt*2 + (m >> 3)) ^ (row & 7);
      Hs[w*16 + row][c8*8 + (m & 7)] = f2h(eluf(acc[nt][r]));
    }
  }
  __syncthreads();
  layer2_out<false>(Hs, w, m, g, g0, (blockIdx.x & (NPART-1))*256,
                    W2t, b2, Eo, part);
}

__global__ __launch_bounds__(256, 2) void k_edge2(
  const float* Xn, const u16* W1f, const float* b1f,
  const u16* W2t, const float* b2,
  bf16* Eo, float* part)
{
  edge_v2<2*NH>(Xn, nullptr, W1f, b1f, W2t, b2, Eo, part);
}
__global__ __launch_bounds__(256, 2) void k_edge4(
  const float* Xn, const bf16* Ein, const u16* W1f, const float* b1f,
  const u16* W2t, const float* b2,
  bf16* Eo, float* part)
{
  edge_v2<3*NH>(Xn, Ein, W1f, b1f, W2t, b2, Eo, part);
}

// ---------------- MLP3 via MFMA: agg(mean of 23 edges) -> H -> H --------------
__global__ __launch_bounds__(128) void k_mlp3(
    const bf16* Ein, const u16* W1f, const float* b1f,
    const u16* W2t, const float* b2,
    float* X3, float* part)
{
  __shared__ __align__(16) u16 Hs[32][NH];   // 8 KB swizzled
  const int j = threadIdx.x;
  const int w = j >> 6, l = j & 63;
  const int m = l & 15, g = l >> 4;
  const int g0 = blockIdx.x*32;
  const int b = g0/(NNODE*NT); const int rem = g0 - b*(NNODE*NT);
  const int n = rem/NT; const int t0 = rem - n*NT;
  const int tr = t0 + w*16 + m;

  float acc32[4][8];
  #pragma unroll
  for(int ks = 0; ks < 4; ks++)
    #pragma unroll
    for(int q = 0; q < 8; q++) acc32[ks][q] = 0.f;
  for(int i = 0; i < NNODE; i++){
    if(i == n) continue;
    const int e = i*23 + (n < i ? n : n - 1);
    const bf16* rowE = Ein + ((size_t)(b*NEDGE + e)*NT + tr)*NH;
    #pragma unroll
    for(int ks = 0; ks < 4; ks++){
      const uint4 rv = *(const uint4*)(rowE + ks*32 + g*8);
      const u32 vv[4] = {rv.x, rv.y, rv.z, rv.w};
      #pragma unroll
      for(int h = 0; h < 4; h++){
        acc32[ks][2*h]   += bl2f((u16)vv[h]);
        acc32[ks][2*h+1] += bl2f((u16)(vv[h] >> 16));
      }
    }
  }
  f16x8 af[4];
  #pragma unroll
  for(int ks = 0; ks < 4; ks++){
    u32 t4[4] = { packf2(acc32[ks][0], acc32[ks][1]), packf2(acc32[ks][2], acc32[ks][3]),
                  packf2(acc32[ks][4], acc32[ks][5]), packf2(acc32[ks][6], acc32[ks][7]) };
    __builtin_memcpy(&af[ks], t4, 16);
  }

  f32x4 acc[8];
  #pragma unroll
  for(int nt = 0; nt < 8; nt++){
    const float bb = b1f[nt*16 + m];
    acc[nt] = (f32x4){bb, bb, bb, bb};
  }
  f16x8 bf0[8], bf1[8];
  #pragma unroll
  for(int nt = 0; nt < 8; nt++)
    bf0[nt] = *(const f16x8*)&W1f[(((nt*4 + 0)*64 + l) << 3)];
  #pragma unroll
  for(int ks = 0; ks < 4; ks++){
    f16x8* cur = (ks & 1) ? bf1 : bf0;
    f16x8* nxt = (ks & 1) ? bf0 : bf1;
    if(ks + 1 < 4){
      #pragma unroll
      for(int nt = 0; nt < 8; nt++)
        nxt[nt] = *(const f16x8*)&W1f[(((nt*4 + ks + 1)*64 + l) << 3)];
    }
    SBAR();
    #pragma unroll
    for(int nt = 0; nt < 8; nt++)
      acc[nt] = __builtin_amdgcn_mfma_f32_16x16x32_f16(af[ks], cur[nt], acc[nt], 0, 0, 0);
    SBAR();
  }
  #pragma unroll
  for(int nt = 0; nt < 8; nt++){
    #pragma unroll
    for(int r = 0; r < 4; r++){
      const int row = g*4 + r;
      const int c8 = (nt*2 + (m >> 3)) ^ (row & 7);
      Hs[w*16 + row][c8*8 + (m & 7)] = f2h(eluf(acc[nt][r]));
    }
  }
  __syncthreads();
  layer2_out<true>(Hs, w, m, g, g0, (blockIdx.x & (NPART-1))*256,
                   W2t, b2, X3, part);
}

// ---------------- GRU: 4 independent (seq,dir) units per 256-thread block -----
// REVERTED to round-17 config: (256,2). Round-18's (256,1) removed the whh
// spill but collapsed occupancy 21%->11% (dur 288->403): residency beats
// spill-purity for this latency-bound kernel.
// encpF/encpR now written in OUTPUT layout (same scatter as outP, zero extra
// cost) so k_add is a fully-linear stream.
__global__ __launch_bounds__(256, 2) void k_gru(
  const bf16* E4,
  const u16* W2F, const float* b2F, const u32* whhPF, const float* bhhF,
  const u16* W2R, const float* b2R, const u32* whhPR, const float* bhhR,
  const float* pw, const float* pb, const float* ew,
  bf16* encpF, bf16* encpR, float* outP, float* hT)
{
  __shared__ __align__(16) u16 xwb16[4][16][196];  // 25088 B (padded rows)
  __shared__ __align__(16) u16 histc[4][16][66];   // 8448 B (chunk-local history)
  __shared__ __align__(16) u16 hs16[4][NR];        // 512 B
  const int tid = threadIdx.x;
  const int u = tid >> 6, c = tid & 63;
  const int gid = blockIdx.x*4 + u;
  const int dir = (gid >= NSEQ) ? 1 : 0;
  const int s = dir ? (gid - NSEQ) : gid;
  const int sb = s / NEDGE, se = s - sb*NEDGE;
  const u16* W2    = dir ? W2R : W2F;
  const float* b2  = dir ? b2R : b2F;
  const u32* whhP  = dir ? whhPR : whhPF;
  const float* bhh = dir ? bhhR : bhhF;
  const float bhr = bhh[c], bhz = bhh[64+c], bhn = bhh[128+c];
  const int m = c & 15, g = c >> 4;   // MFMA lane decomposition

  hs16[u][c] = 0;
  float hprev = 0.f;

  for(int T = 0; T < 4; T++){
    const int t_m = dir ? (NT - 1 - (T*16 + m)) : (T*16 + m);
    const bf16* arow = E4 + ((size_t)s*NT + t_m)*NH;
    f16x8 afr[4];
    #pragma unroll
    for(int ks = 0; ks < 4; ks++){
      const uint4 rv = *(const uint4*)(arow + ks*32 + g*8);
      u32 tmp[4] = { bf2h2(rv.x), bf2h2(rv.y), bf2h2(rv.z), bf2h2(rv.w) };
      f16x8 a; __builtin_memcpy(&a, tmp, 16);
      afr[ks] = a;
    }
    for(int nt = 0; nt < 12; nt++){
      f32x4 acc = {0.f, 0.f, 0.f, 0.f};
      #pragma unroll
      for(int ks = 0; ks < 4; ks++){
        const f16x8 bfr = *(const f16x8*)&W2[(((nt*4 + ks)*64 + c) << 3)];
        acc = __builtin_amdgcn_mfma_f32_16x16x32_f16(afr[ks], bfr, acc, 0, 0, 0);
      }
      const float bb = b2[nt*16 + m];
      #pragma unroll
      for(int r = 0; r < 4; r++)
        xwb16[u][g*4 + r][nt*16 + m] = f2h(acc[r] + bb);
    }
    u32 zofs = 0;
    asm volatile("" : "+v"(zofs));       // opaque VGPR zero: prevent hoist/CSE
    const u32* wPt = whhP + zofs;
    u32 wr2[32], wz2[32], wn2[32];
    #pragma unroll
    for(int kk = 0; kk < 32; kk++){
      wr2[kk] = wPt[kk*192 + c];
      wz2[kk] = wPt[kk*192 + 64 + c];
      wn2[kk] = wPt[kk*192 + 128 + c];
    }
    for(int pp = 0; pp < 16; pp++){
      const float xr = h2f(xwb16[u][pp][c]);
      const float xz = h2f(xwb16[u][pp][64 + c]);
      const float xn = h2f(xwb16[u][pp][128 + c]);
      float hr = bhr, hz = bhz, hn = bhn;
      #pragma unroll
      for(int q = 0; q < 8; q++){
        const uint4 hq = *(const uint4*)&hs16[u][8*q];
        hr = dot2(hq.x, wr2[4*q], hr);   hr = dot2(hq.y, wr2[4*q+1], hr);
        hr = dot2(hq.z, wr2[4*q+2], hr); hr = dot2(hq.w, wr2[4*q+3], hr);
        hz = dot2(hq.x, wz2[4*q], hz);   hz = dot2(hq.y, wz2[4*q+1], hz);
        hz = dot2(hq.z, wz2[4*q+2], hz); hz = dot2(hq.w, wz2[4*q+3], hz);
        hn = dot2(hq.x, wn2[4*q], hn);   hn = dot2(hq.y, wn2[4*q+1], hn);
        hn = dot2(hq.z, wn2[4*q+2], hn); hn = dot2(hq.w, wn2[4*q+3], hn);
      }
      const float rg = sigmf(xr + hr);
      const float zg = sigmf(xz + hz);
      const float ng = tanhfast(xn + rg*hn);
      const float hnew = (1.f - zg)*ng + zg*hprev;
      const u16 hbits = f2h(hnew);
      hs16[u][c] = hbits; hprev = hnew;
      histc[u][pp][c] = hbits;
    }
    {
      const int tt = c & 15, grp = c >> 4;
      const int p0 = T*16 + tt;
      const int tg = dir ? (NT - 1 - p0) : p0;
      const size_t oidx = (((size_t)(sb*NT + tg))*NEDGE + se)*NNE + grp;
      if(!dir){
        float ap = pb[grp], ae = 0.f;
        for(int kk = 0; kk < 32; kk++){
          u32 hp; __builtin_memcpy(&hp, &histc[u][tt][2*kk], 4);
          const float h0 = h2f((u16)hp), h1 = h2f((u16)(hp >> 16));
          ap += h0*pw[(2*kk)*NNE + grp] + h1*pw[(2*kk+1)*NNE + grp];
          ae += h0*ew[(2*kk)*NNE + grp] + h1*ew[(2*kk+1)*NNE + grp];
        }
        outP[oidx] = ap;
        encpF[oidx] = __float2bfloat16(ae);
      } else {
        float ae = 0.f;
        for(int kk = 0; kk < 32; kk++){
          u32 hp; __builtin_memcpy(&hp, &histc[u][tt][2*kk], 4);
          const float h0 = h2f((u16)hp), h1 = h2f((u16)(hp >> 16));
          ae += h0*ew[(NR + 2*kk)*NNE + grp] + h1*ew[(NR + 2*kk+1)*NNE + grp];
        }
        encpR[oidx] = __float2bfloat16(ae);
      }
    }
  }
  if(!dir) hT[(size_t)s*NR + c] = hprev;
}

// ---------------- merge enc halves + bias (fully linear, vectorized) ---------
__global__ void k_add(const bf16* eF, const bf16* eR, const float* eb, float* outE){
  const int i4 = blockIdx.x*256 + threadIdx.x;   // group of 4 elements (one NNE)
  if(i4 >= PRIOR_SZ/4) return;
  const uint2 f = ((const uint2*)eF)[i4];
  const uint2 r = ((const uint2*)eR)[i4];
  float4 o;
  o.x = bl2f((u16)f.x)        + bl2f((u16)r.x)        + eb[0];
  o.y = bl2f((u16)(f.x >> 16)) + bl2f((u16)(r.x >> 16)) + eb[1];
  o.z = bl2f((u16)f.y)        + bl2f((u16)r.y)        + eb[2];
  o.w = bl2f((u16)(f.y >> 16)) + bl2f((u16)(r.y >> 16)) + eb[3];
  ((float4*)outE)[i4] = o;
}

extern "C" void kernel_launch(void* const* d_in, const int* in_sizes, int n_in,
                              void* d_out, int out_size, void* d_ws, size_t ws_size,
                              hipStream_t stream)
{
  const size_t NEED = 79511552ull;   // unchanged; known ws >= 83,181,568
  if(ws_size < NEED){
    k_fill<<<(out_size + 255)/256, 256, 0, stream>>>((float*)d_out, out_size, 3584.0f);
    return;
  }
  const float* inp  = (const float*)d_in[0];
  const float* m1w1 = (const float*)d_in[1];  const float* m1b1 = (const float*)d_in[2];
  const float* m1w2 = (const float*)d_in[3];  const float* m1b2 = (const float*)d_in[4];
  const float* m1g  = (const float*)d_in[5];  const float* m1be = (const float*)d_in[6];
  const float* m2w1 = (const float*)d_in[7];  const float* m2b1 = (const float*)d_in[8];
  const float* m2w2 = (const float*)d_in[9];  const float* m2b2 = (const float*)d_in[10];
  const float* m2g  = (const float*)d_in[11]; const float* m2be = (const float*)d_in[12];
  const float* m3w1 = (const float*)d_in[13]; const float* m3b1 = (const float*)d_in[14];
  const float* m3w2 = (const float*)d_in[15]; const float* m3b2 = (const float*)d_in[16];
  const float* m3g  = (const float*)d_in[17]; const float* m3be = (const float*)d_in[18];
  const float* m4w1 = (const float*)d_in[19]; const float* m4b1 = (const float*)d_in[20];
  const float* m4w2 = (const float*)d_in[21]; const float* m4b2 = (const float*)d_in[22];
  const float* m4g  = (const float*)d_in[23]; const float* m4be = (const float*)d_in[24];
  const float* wihF = (const float*)d_in[25]; const float* whhF = (const float*)d_in[26];
  const float* bihF = (const float*)d_in[27]; const float* bhhF = (const float*)d_in[28];
  const float* wihR = (const float*)d_in[29]; const float* whhR = (const float*)d_in[30];
  const float* bihR = (const float*)d_in[31]; const float* bhhR = (const float*)d_in[32];
  const float* pw   = (const float*)d_in[33]; const float* pb   = (const float*)d_in[34];
  const float* ew   = (const float*)d_in[35]; const float* eb   = (const float*)d_in[36];

  char* ws = (char*)d_ws;
  float* AUX = (float*)(ws + 0);             // 16 KB reserved (SC/SH/B1F)
  char*  Xr  = ws + 16384;                   // 6,291,456 B (X1 then X3)
  float* X   = (float*)Xr;
  bf16*  E   = (bf16*)(ws + 16384 + 6291456); // 72,351,744 B (E2 then in-place E4)
  char*  WP  = ws + 78659584;                // 327,680 B MLP weight tables (frag-ordered)
  u16* W1f2 = (u16*)(WP + 0);                // 65,536 B (128 x 256, BN-folded)
  u16* W2t2 = (u16*)(WP + 65536);            // 32,768 B
  u16* W1f4 = (u16*)(WP + 98304);            // 98,304 B (128 x 384, BN-folded)
  u16* W2t4 = (u16*)(WP + 196608);           // 32,768 B
  u16* W2t1 = (u16*)(WP + 229376);           // 32,768 B
  u16* W2t3 = (u16*)(WP + 262144);           // 32,768 B
  u16* W1f3 = (u16*)(WP + 294912);           // 32,768 B (128 x 128, BN/23-folded)
  float* PART = (float*)(ws + 78987264);     // 524,288 B: 4 stages x NPART x 256 f32
  float* P0 = PART + 0*NPART*256;
  float* P1 = PART + 1*NPART*256;
  float* P2 = PART + 2*NPART*256;
  float* P3 = PART + 3*NPART*256;
  // aliases inside X region, valid AFTER mlp4 has consumed X3:
  u16*  W2F   = (u16*)(Xr + 0);              // 49,152 B (BN-folded wih fwd, frag-ordered)
  u16*  W2R   = (u16*)(Xr + 49152);          // 49,152 B -> 98,304
  u32*  whhPF = (u32*)(Xr + 98304);          // 24,576 B -> 122,880
  u32*  whhPR = (u32*)(Xr + 122880);         // 24,576 B -> 147,456
  float* b2F  = (float*)(Xr + 147456);       // 768 B -> 148,224
  float* b2R  = (float*)(Xr + 148224);       // 768 B -> 148,992
  bf16* encpF = (bf16*)(Xr + 148992);        // 2,260,992 B -> 2,409,984
  bf16* encpR = (bf16*)(Xr + 2409984);       // 2,260,992 B -> 4,670,976 <= 6,291,456

  float* SC0  = AUX + 1024 + 0*128; float* SC1  = AUX + 1024 + 1*128;
  float* SC2  = AUX + 1024 + 2*128; float* SC3  = AUX + 1024 + 3*128;
  float* SH0  = AUX + 1536 + 0*128; float* SH1  = AUX + 1536 + 1*128;
  float* SH2  = AUX + 1536 + 2*128; float* SH3  = AUX + 1536 + 3*128;
  float* B1F2 = AUX + 2048;                  // 128 f32 folded biases
  float* B1F4 = AUX + 2176;
  float* B1F3 = AUX + 2304;                  // -> word 2432 < 4096

  float* outP = (float*)d_out;
  float* outE = outP + PRIOR_SZ;
  float* hT   = outP + 2*PRIOR_SZ;

  k_prep_mlp<<<64, 256, 0, stream>>>(m1w2, m2w2, m3w2, m4w2,
                                     W2t1, W2t2, W2t3, W2t4, PART);
  k_mlp1<<<ROWS1/32, 128, 0, stream>>>(inp, m1w1, m1b1, W2t1, m1b2, X, P0);
  k_bn<<<1, 128, 0, stream>>>(P0, m1g, m1be, 1.f/ROWS1, SC0, SH0);
  k_fold<<<128, 128, 0, stream>>>(m2w1, 2*NH, 1.f, SC0, SH0, SC0, SH0, m2b1, W1f2, B1F2);
  k_edge2<<<ROWS2/64, 256, 0, stream>>>(X, W1f2, B1F2, W2t2, m2b2, E, P1);
  k_bn<<<1, 128, 0, stream>>>(P1, m2g, m2be, 1.f/ROWS2, SC1, SH1);
  k_fold<<<128, 128, 0, stream>>>(m3w1, NH, 1.f/23.f, SC1, SH1, SC1, SH1, m3b1, W1f3, B1F3);
  k_mlp3<<<ROWS1/32, 128, 0, stream>>>(E, W1f3, B1F3, W2t3, m3b2, X, P2);
  k_bn<<<1, 128, 0, stream>>>(P2, m3g, m3be, 1.f/ROWS1, SC2, SH2);
  k_fold<<<128, 128, 0, stream>>>(m4w1, 3*NH, 1.f, SC2, SH2, SC1, SH1, m4b1, W1f4, B1F4);
  k_edge4<<<ROWS2/64, 256, 0, stream>>>(X, E, W1f4, B1F4, W2t4, m4b2, E, P3);
  k_bn<<<1, 128, 0, stream>>>(P3, m4g, m4be, 1.f/ROWS2, SC3, SH3);
  // X region is now dead -> pack GRU weights (BN folded, frag-ordered) into it
  k_prep2<<<96, 256, 0, stream>>>(wihF, whhF, wihR, whhR, SC3, SH3, bihF, bihR,
                                  W2F, W2R, b2F, b2R, whhPF, whhPR);
  k_gru<<<(2*NSEQ)/4, 256, 0, stream>>>(E,
                                  W2F, b2F, whhPF, bhhF,
                                  W2R, b2R, whhPR, bhhR,
                                  pw, pb, ew, encpF, encpR, outP, hT);
  k_add<<<(PRIOR_SZ/4 + 255)/256, 256, 0, stream>>>(encpF, encpR, eb, outE);
}